// Round 13
// baseline (500.945 us; speedup 1.0000x reference)
//
#include <hip/hip_runtime.h>
#include <hip/hip_bf16.h>

// Problem constants
#define B_   2
#define C_   64
#define H_   96
#define W_   192
#define D_   48
#define G_   8
#define OUT_ 32
#define HW_  (H_ * W_)   // 18432

// Padded f16 correlation volume: (B, DP, HP, WP, 8) halfs, halo = 4
#define DP_ 56
#define HP_ 104
#define WP_ 200
#define PLANE_ (HP_ * WP_ * 8)          // halfs per d-plane = 166400
#define BASEH_HALFS (B_ * DP_ * PLANE_) // 18,636,800 halfs = 37.27 MB

// Workspace layout (float offsets)
#define OFF_BASEH 4718592                  // f16 padded volume      9,318,400 float-slots
#define OFF_SW    14036992                 // (3,B*HW) fp32            110,592
#define OFF_BPACK 14147584                 // f16 B-frags               10,752 float-slots
#define OFF_WP1T  14158336                 // (65,9,32) fp32            18,720

typedef _Float16 f16x8  __attribute__((ext_vector_type(8)));
typedef float    f32x4  __attribute__((ext_vector_type(4)));
typedef float    f32x16 __attribute__((ext_vector_type(16)));

// ---------------------------------------------------------------------------
// Kernel 0: weight prep for 32x32x16 MFMA.
//  bpack[((k*14+c)*64+lane)*8+j] = f16( V_k[tap(c,hf)][gi=j][n=lane&31] )
//  hf = lane>>5. Chunk->tap mapping (must match fused kernel's addressing):
//   c in [0,9):  kd = hf? +1 : -1 ; kh = c/3-1 ; kw = c%3-1
//   c in [9,12): kd = 0 ; kh = hf? +1 : -1 ; kw = (c-9)-1
//   c == 12:     kd = 0 ; kh = 0 ; kw = hf? +1 : -1
//   c == 13:     hf==0 -> center (0,0,0) ; hf==1 -> zero pad
//  V_k[tap][gi][n] = sum_g w_final[n*8+g] * w_k[(g*8+gi)*27+tap]
//  part B: wp1T[ic][t][oc] = w_pred1[oc][ic][t]
// ---------------------------------------------------------------------------
__global__ void wtrans_kernel(const float* __restrict__ w_s,
                              const float* __restrict__ w_m,
                              const float* __restrict__ w_l,
                              const float* __restrict__ w_final,
                              const float* __restrict__ w_pred1,
                              _Float16* __restrict__ bpack,
                              float* __restrict__ wp1T) {
    int i = blockIdx.x * 256 + threadIdx.x;
    if (i < 21504) {
        int j = i & 7;                 // gi
        int lane = (i >> 3) & 63;
        int kc = i >> 9;               // 0..41
        int c = kc % 14, k = kc / 14;
        int hf = lane >> 5, n = lane & 31;
        int kd = 0, kh = 0, kw = 0; bool valid = true;
        if (c < 9)        { kd = hf ? 1 : -1; kh = c / 3 - 1; kw = c % 3 - 1; }
        else if (c < 12)  { kd = 0; kh = hf ? 1 : -1; kw = (c - 9) - 1; }
        else if (c == 12) { kd = 0; kh = 0; kw = hf ? 1 : -1; }
        else              { valid = (hf == 0); }
        float val = 0.f;
        if (valid) {
            int tap = (kd + 1) * 9 + (kh + 1) * 3 + (kw + 1);
            const float* wsel = (k == 0) ? w_s : (k == 1) ? w_m : w_l;
            #pragma unroll
            for (int g = 0; g < 8; ++g)
                val += w_final[n * 8 + g] * wsel[(g * 8 + j) * 27 + tap];
        }
        bpack[i] = (_Float16)val;
    } else if (i < 21504 + 18720) {
        int j = i - 21504;
        int oc = j & 31; int it = j >> 5; int ic = it / 9; int t = it - ic * 9;
        wp1T[j] = w_pred1[(oc * 65 + ic) * 9 + t];
    }
}

// ---------------------------------------------------------------------------
// Kernel 2+3 MERGED (R13): corr (norm fused, R4 numerics) + pred (ic-split
//  x4, R10 numerics) in ONE dispatch. The two are mutually independent
//  (corr: feat_l,feat_r -> baseh; pred: feat_l,edge,wp1T -> swp) but were
//  serialized on the stream (~50 µs). Merged grid = 1152 corr blocks +
//  576 pred blocks; pred's latency-bound blocks fill CU slots while corr
//  drains. Branch is block-uniform (no divergence). LDS = union:
//  corr needs 80*68 floats (21.8 KB), pred needs 3*64*33 (25.3 KB).
//  Both paths' numerics are bit-identical to their proven versions.
// ---------------------------------------------------------------------------
__global__ __launch_bounds__(256) void corrpred_kernel(
        const float* __restrict__ feat_l,
        const float* __restrict__ feat_r,
        _Float16* __restrict__ baseh,
        const float* __restrict__ edge,
        const float* __restrict__ wp1T,
        const float* __restrict__ gamma,
        const float* __restrict__ beta,
        const float* __restrict__ mean,
        const float* __restrict__ var,
        const float* __restrict__ w2,
        const float* __restrict__ b2,
        const float* __restrict__ temp,
        float* __restrict__ swp) {
    __shared__ float sh[3 * 64 * 33];   // 25,344 B = union(frl 5440f, red 6336f)
    int tid = threadIdx.x;
    int bid = blockIdx.x;

    if (bid < 1152) {
        // ================= corr path (R4/R12 numerics) =================
        float* frl = sh;                 // [80*68]
        int bx = bid % 6;
        int r0 = bid / 6;
        int h  = r0 % 96;
        int b  = r0 / 96;
        int w0 = bx * 32;
        int wbase = w0 - 48;             // LDS window start (may be < 0)

        // stage + normalize feat_r window: 8 g x 80 iw pairs
        for (int p = tid; p < 640; p += 256) {
            int gg = p / 80;
            int iw = p - gg * 80;
            int wg = wbase + iw;
            if (wg >= 0) {
                const float* src = feat_r + (size_t)(b * 64 + gg * 8) * HW_ + h * W_ + wg;
                float v[8]; float s = 0.f;
                #pragma unroll
                for (int c = 0; c < 8; ++c) { v[c] = src[(size_t)c * HW_]; s += v[c] * v[c]; }
                float inv = 0.35355339059327373f / fmaxf(sqrtf(s), 1e-12f);  // incl 1/sqrt(8)
                #pragma unroll
                for (int c = 0; c < 8; ++c) frl[iw * 68 + gg * 8 + c] = v[c] * inv;
            }
        }

        // own fl vector, normalized (no 1/sqrt(8) here)
        int g = tid & 7, wi = tid >> 3;
        int w = w0 + wi;
        const float* fls = feat_l + (size_t)(b * 64 + g * 8) * HW_ + h * W_ + w;
        float a[8]; float s = 0.f;
        #pragma unroll
        for (int c = 0; c < 8; ++c) { a[c] = fls[(size_t)c * HW_]; s += a[c] * a[c]; }
        float inv = 1.0f / fmaxf(sqrtf(s), 1e-12f);
        #pragma unroll
        for (int c = 0; c < 8; ++c) a[c] *= inv;

        __syncthreads();

        _Float16* dst = baseh + (size_t)((b * DP_ + 4) * HP_ + 4 + h) * WP_ * 8 + (size_t)(4 + w) * 8 + g;
        for (int d = 0; d < D_; ++d) {
            int wd = w - d;
            float acc = 0.f;
            if (wd >= 0) {
                const float* fr = frl + (wd - wbase) * 68 + g * 8;
                acc = a[0]*fr[0] + a[1]*fr[1] + a[2]*fr[2] + a[3]*fr[3]
                    + a[4]*fr[4] + a[5]*fr[5] + a[6]*fr[6] + a[7]*fr[7];
            }
            dst[(size_t)d * PLANE_] = (_Float16)acc;
        }
        return;
    }

    // ================= pred path (R10 numerics) =================
    // red[g][px][oc] -> sh[g*2112 + px*33 + oc]  (pad 33: conflict-free)
    int px  = tid & 63;
    int grp = tid >> 6;                // 0..3 ic-groups
    int pid = (bid - 1152) * 64 + px;  // 0..36863
    int b = pid / HW_; int hw = pid - b * HW_;
    int h = hw / W_;   int w = hw - h * W_;

    int ic0 = grp * 17;
    int ic1 = (grp == 3) ? 65 : ic0 + 17;

    float acc[32];
    #pragma unroll
    for (int i = 0; i < 32; ++i) acc[i] = 0.f;

    for (int ic = ic0; ic < ic1; ++ic) {
        const float* src = (ic < 64) ? (feat_l + (size_t)(b * 64 + ic) * HW_)
                                     : (edge + (size_t)b * HW_);
        float v[9];
        #pragma unroll
        for (int ky = 0; ky < 3; ++ky) {
            int y = h + ky - 1;
            #pragma unroll
            for (int kx = 0; kx < 3; ++kx) {
                int x = w + kx - 1;
                bool ok = (y >= 0) && (y < H_) && (x >= 0) && (x < W_);
                v[ky * 3 + kx] = ok ? src[y * W_ + x] : 0.f;
            }
        }
        #pragma unroll
        for (int t = 0; t < 9; ++t) {
            const float* wrow = wp1T + (ic * 9 + t) * 32;
            float vv = v[t];
            #pragma unroll
            for (int oc = 0; oc < 32; ++oc) acc[oc] = fmaf(vv, wrow[oc], acc[oc]);
        }
    }

    if (grp) {
        #pragma unroll
        for (int oc = 0; oc < 32; ++oc) sh[(grp - 1) * 2112 + px * 33 + oc] = acc[oc];
    }
    __syncthreads();
    if (grp == 0) {
        #pragma unroll
        for (int oc = 0; oc < 32; ++oc)
            acc[oc] += sh[0 * 2112 + px * 33 + oc]
                     + sh[1 * 2112 + px * 33 + oc]
                     + sh[2 * 2112 + px * 33 + oc];

        float l0 = b2[0], l1 = b2[1], l2 = b2[2];
        #pragma unroll
        for (int oc = 0; oc < 32; ++oc) {
            float sc = gamma[oc] / sqrtf(var[oc] + 1e-5f);
            float xb = (acc[oc] - mean[oc]) * sc + beta[oc];
            float r = fmaxf(xb, 0.f);
            l0 = fmaf(w2[0 * 32 + oc], r, l0);
            l1 = fmaf(w2[1 * 32 + oc], r, l1);
            l2 = fmaf(w2[2 * 32 + oc], r, l2);
        }
        float t = fmaxf(temp[0], 0.1f);
        float it = 1.0f / t;
        l0 *= it; l1 *= it; l2 *= it;
        float m = fmaxf(l0, fmaxf(l1, l2));
        float e0 = __expf(l0 - m), e1 = __expf(l1 - m), e2 = __expf(l2 - m);
        float is = 1.0f / (e0 + e1 + e2);
        swp[0 * (B_ * HW_) + pid] = e0 * is;
        swp[1 * (B_ * HW_) + pid] = e1 * is;
        swp[2 * (B_ * HW_) + pid] = e2 * is;
    }
}

// ---------------------------------------------------------------------------
// Kernel 4: MFMA 32x32x16 fused conv — R8 EXACT (best config; ~136 µs).
//  256 thr / (256,2), grid (6,48,B*4) = 2304 blocks (d-sweep 6, refill-depth
//  win), LDS-B 43 KB, chunk-288 XCD swizzle, sw folded into A via pk_mul,
//  2 interleaved acc chains, opaque-index anti-LICM.
//  Closed directions (all measured neutral-to-negative): 8-wave blocks (R4,
//  VGPR collapse), 3-chain epilogue-sw (R6, VGPR collapse), explicit av[42]
//  batch (R7), batch+setprio (R9), launch_bounds(256,4) (R1, spills),
//  halo-zero corr fusion (R11, +19 µs scattered stores).
//  D: col = lane&31 = o, row = (reg&3)+8*(reg>>2)+4*hf = w-offset.
// ---------------------------------------------------------------------------
__global__ __launch_bounds__(256, 2) void fusedconv_mfma32(
        const _Float16* __restrict__ baseh,
        const float* __restrict__ swp,
        const _Float16* __restrict__ bpack,
        const float* __restrict__ bf,
        float* __restrict__ out) {
    __shared__ _Float16 bsh[3 * 14 * 64 * 8];   // 43,008 B

    int tid = threadIdx.x;
    // stage bpack -> LDS (2688 f16x8 chunks)
    {
        const f16x8* srcv = (const f16x8*)bpack;
        f16x8* dstv = (f16x8*)bsh;
        for (int i = tid; i < 2688; i += 256) dstv[i] = srcv[i];
    }

    // XCD-aware bijective swizzle of the linear block id (nwg = 2304 = 8*288)
    int L   = blockIdx.x + 6 * (blockIdx.y + 48 * blockIdx.z);
    int sL  = (L & 7) * 288 + (L >> 3);
    int bx  = sL % 6;
    int byz = sL / 6;
    int by  = byz % 48;
    int bz  = byz / 48;          // 0..7

    int wave = tid >> 6, lane = tid & 63;
    int m = lane & 31, hf = lane >> 5;
    int hh = wave >> 1, dh = wave & 1;
    int w0 = bx * 32;
    int h  = by * 2 + hh;
    int b  = bz >> 2;            // 0..1
    int dq = bz & 3;             // 0..3
    int d0 = dq * 12 + dh * 6;   // 6-d sweep per wave

    // softmax weights as f16 splats (per-lane row m)
    f16x8 swh[3];
    #pragma unroll
    for (int k = 0; k < 3; ++k) {
        float s = swp[k * (B_ * HW_) + b * HW_ + h * W_ + w0 + m];
        _Float16 hs = (_Float16)s;
        f16x8 t;
        #pragma unroll
        for (int j = 0; j < 8; ++j) t[j] = hs;
        swh[k] = t;
    }

    // half-wave address deltas per (scale, class), bytes
    int hdv[3][4];
    #pragma unroll
    for (int k = 0; k < 3; ++k) {
        int dil = 1 << k;
        hdv[k][0] = hf * (2 * dil * HP_ * WP_ * 8 * 2);
        hdv[k][1] = hf * (2 * dil * WP_ * 8 * 2);
        hdv[k][2] = hf * (2 * dil * 8 * 2);
        hdv[k][3] = 0;
    }

    const char* bb = (const char*)baseh;
    char*       ob = (char*)out;

    // byte offset of interior origin (d0-plane, h, w0+m)
    unsigned pm = (unsigned)(((((b * DP_ + 4 + d0) * HP_ + 4 + h) * WP_ + 4 + w0 + m) * 8) * 2);
    float bias = bf[m];   // o = lane&31
    unsigned outoff = (unsigned)((((b * OUT_ + m) * D_ + d0) * HW_ + h * W_ + w0 + 4 * hf) * 4);

    __syncthreads();

    for (int d = 0; d < 6; ++d) {
        // opaque per-iteration LDS byte offset (value lane*16): defeats LICM/hoist
        unsigned bofs = (unsigned)(lane * 16);
        asm volatile("" : "+v"(bofs));
        const char* bshp = (const char*)bsh + bofs;

        f32x16 acc0, acc1;
        #pragma unroll
        for (int i = 0; i < 16; ++i) { acc0[i] = 0.f; acc1[i] = 0.f; }
        #pragma unroll
        for (int k = 0; k < 3; ++k) {
            int dil = 1 << k;
            #pragma unroll
            for (int c = 0; c < 14; ++c) {
                int coff, cls;
                if (c < 9)        { coff = ((-dil * HP_ + (c / 3 - 1) * dil) * WP_ * 8 + (c % 3 - 1) * dil * 8) * 2; cls = 0; }
                else if (c < 12)  { coff = ((-dil) * WP_ * 8 + ((c - 9) - 1) * dil * 8) * 2;                          cls = 1; }
                else if (c == 12) { coff = -dil * 16;                                                                  cls = 2; }
                else              { coff = 0;                                                                          cls = 3; }
                unsigned a = pm + (unsigned)(hdv[k][cls] + coff);
                f16x8 av = *(const f16x8*)(bb + a);
                f16x8 Bv = *(const f16x8*)(bshp + (k * 14 + c) * 1024);
                av = av * swh[k];
                if (c & 1) acc1 = __builtin_amdgcn_mfma_f32_32x32x16_f16(av, Bv, acc1, 0, 0, 0);
                else       acc0 = __builtin_amdgcn_mfma_f32_32x32x16_f16(av, Bv, acc0, 0, 0, 0);
            }
        }
        #pragma unroll
        for (int q = 0; q < 4; ++q) {
            f32x4 v;
            #pragma unroll
            for (int i = 0; i < 4; ++i) v[i] = acc0[4 * q + i] + acc1[4 * q + i] + bias;
            *(f32x4*)(ob + outoff + q * 32) = v;   // rows 8q+4hf..+3, o = m
        }
        pm += PLANE_ * 2;
        outoff += HW_ * 4;
    }
}

// ---------------------------------------------------------------------------
extern "C" void kernel_launch(void* const* d_in, const int* in_sizes, int n_in,
                              void* d_out, int out_size, void* d_ws, size_t ws_size,
                              hipStream_t stream) {
    const float* feat_l   = (const float*)d_in[0];
    const float* feat_r   = (const float*)d_in[1];
    const float* edge     = (const float*)d_in[2];
    const float* w_pred1  = (const float*)d_in[3];
    const float* bn_gamma = (const float*)d_in[4];
    const float* bn_beta  = (const float*)d_in[5];
    const float* bn_mean  = (const float*)d_in[6];
    const float* bn_var   = (const float*)d_in[7];
    const float* w_pred2  = (const float*)d_in[8];
    const float* b_pred2  = (const float*)d_in[9];
    const float* temp     = (const float*)d_in[10];
    const float* w_s      = (const float*)d_in[11];
    const float* w_m      = (const float*)d_in[12];
    const float* w_l      = (const float*)d_in[13];
    const float* w_final  = (const float*)d_in[14];
    const float* b_final  = (const float*)d_in[15];
    float* out = (float*)d_out;

    float* ws = (float*)d_ws;
    _Float16*  baseh = (_Float16*)(ws + OFF_BASEH);
    float*     swp   = ws + OFF_SW;
    _Float16*  bpack = (_Float16*)(ws + OFF_BPACK);
    float*     wp1T  = ws + OFF_WP1T;

    // 0: weight prep (must precede corrpred: pred path reads wp1T)
    wtrans_kernel<<<dim3(158), 256, 0, stream>>>(w_s, w_m, w_l, w_final, w_pred1, bpack, wp1T);
    // zero the padded volume (halo must be 0; ws is poisoned each launch).
    // Runtime fill streams at ~6 TB/s — measured better than in-kernel
    // halo zeroing (R11: +19 µs).
    hipMemsetAsync(baseh, 0, (size_t)BASEH_HALFS * sizeof(_Float16), stream);
    // 2+3: corr (1152 blocks) + pred (576 blocks) merged — independent work
    //      overlapped in one dispatch (R13 single-variable test)
    corrpred_kernel<<<dim3(1152 + 576), 256, 0, stream>>>(feat_l, feat_r, baseh,
                                                          edge, wp1T, bn_gamma,
                                                          bn_beta, bn_mean, bn_var,
                                                          w_pred2, b_pred2, temp, swp);
    // 4: MFMA 32x32 fused conv (R8 exact)
    fusedconv_mfma32<<<dim3(W_ / 32, H_ / 2, B_ * 4), 256, 0, stream>>>(baseh, swp, bpack, b_final, out);
}

// Round 14
// 476.747 us; speedup vs baseline: 1.0508x; 1.0508x over previous
//
#include <hip/hip_runtime.h>
#include <hip/hip_bf16.h>

// Problem constants
#define B_   2
#define C_   64
#define H_   96
#define W_   192
#define D_   48
#define G_   8
#define OUT_ 32
#define HW_  (H_ * W_)   // 18432

// Padded f16 correlation volume: (B, DP, HP, WP, 8) halfs, halo = 4
#define DP_ 56
#define HP_ 104
#define WP_ 200
#define PLANE_ (HP_ * WP_ * 8)          // halfs per d-plane = 166400
#define BASEH_HALFS (B_ * DP_ * PLANE_) // 18,636,800 halfs = 37.27 MB

// Workspace layout (float offsets)
#define OFF_BASEH 4718592                  // f16 padded volume      9,318,400 float-slots
#define OFF_SW    14036992                 // (3,B*HW) fp32            110,592
#define OFF_BPACK 14147584                 // f16 B-frags               10,752 float-slots
#define OFF_WP1T  14158336                 // (65,9,32) fp32            18,720

typedef _Float16 f16x8  __attribute__((ext_vector_type(8)));
typedef float    f32x4  __attribute__((ext_vector_type(4)));
typedef float    f32x16 __attribute__((ext_vector_type(16)));

// ---------------------------------------------------------------------------
// Kernel 0: weight prep for 32x32x16 MFMA.
//  bpack[((k*14+c)*64+lane)*8+j] = f16( V_k[tap(c,hf)][gi=j][n=lane&31] )
//  hf = lane>>5. Chunk->tap mapping (must match fused kernel's addressing):
//   c in [0,9):  kd = hf? +1 : -1 ; kh = c/3-1 ; kw = c%3-1
//   c in [9,12): kd = 0 ; kh = hf? +1 : -1 ; kw = (c-9)-1
//   c == 12:     kd = 0 ; kh = 0 ; kw = hf? +1 : -1
//   c == 13:     hf==0 -> center (0,0,0) ; hf==1 -> zero pad
//  V_k[tap][gi][n] = sum_g w_final[n*8+g] * w_k[(g*8+gi)*27+tap]
//  part B: wp1T[ic][t][oc] = w_pred1[oc][ic][t]
// ---------------------------------------------------------------------------
__global__ void wtrans_kernel(const float* __restrict__ w_s,
                              const float* __restrict__ w_m,
                              const float* __restrict__ w_l,
                              const float* __restrict__ w_final,
                              const float* __restrict__ w_pred1,
                              _Float16* __restrict__ bpack,
                              float* __restrict__ wp1T) {
    int i = blockIdx.x * 256 + threadIdx.x;
    if (i < 21504) {
        int j = i & 7;                 // gi
        int lane = (i >> 3) & 63;
        int kc = i >> 9;               // 0..41
        int c = kc % 14, k = kc / 14;
        int hf = lane >> 5, n = lane & 31;
        int kd = 0, kh = 0, kw = 0; bool valid = true;
        if (c < 9)        { kd = hf ? 1 : -1; kh = c / 3 - 1; kw = c % 3 - 1; }
        else if (c < 12)  { kd = 0; kh = hf ? 1 : -1; kw = (c - 9) - 1; }
        else if (c == 12) { kd = 0; kh = 0; kw = hf ? 1 : -1; }
        else              { valid = (hf == 0); }
        float val = 0.f;
        if (valid) {
            int tap = (kd + 1) * 9 + (kh + 1) * 3 + (kw + 1);
            const float* wsel = (k == 0) ? w_s : (k == 1) ? w_m : w_l;
            #pragma unroll
            for (int g = 0; g < 8; ++g)
                val += w_final[n * 8 + g] * wsel[(g * 8 + j) * 27 + tap];
        }
        bpack[i] = (_Float16)val;
    } else if (i < 21504 + 18720) {
        int j = i - 21504;
        int oc = j & 31; int it = j >> 5; int ic = it / 9; int t = it - ic * 9;
        wp1T[j] = w_pred1[(oc * 65 + ic) * 9 + t];
    }
}

// ---------------------------------------------------------------------------
// Kernel 2 (norm fused in, R4 — proven ~48 µs win): correlation volume ->
//  padded f16 volume. Block = (32 w) x (8 g) at one (h,b). Stages the
//  80-column feat_r window [w0-48, w0+32) into LDS, L2-normalizing each
//  (g,w) 8-vector on the fly (1/sqrt(8) folded in). Own fl vector normalized
//  in registers. LDS stride 68 staggers banks.
//  Closed: halo-zero fusion (R11 +19 µs); merge with pred (R13 +23 µs —
//  union codegen collapsed VGPR to 64, exposed the 8-way LDS conflict).
// ---------------------------------------------------------------------------
__global__ __launch_bounds__(256) void corr_kernel(const float* __restrict__ feat_l,
                                                   const float* __restrict__ feat_r,
                                                   _Float16* __restrict__ baseh) {
    __shared__ float frl[80 * 68];   // 21,760 B
    int tid = threadIdx.x;
    int h = blockIdx.y;
    int b = blockIdx.z;
    int w0 = blockIdx.x * 32;
    int wbase = w0 - 48;             // LDS window start (may be < 0)

    // stage + normalize feat_r window: 8 g x 80 iw pairs
    for (int p = tid; p < 640; p += 256) {
        int gg = p / 80;
        int iw = p - gg * 80;
        int wg = wbase + iw;
        if (wg >= 0) {
            const float* src = feat_r + (size_t)(b * 64 + gg * 8) * HW_ + h * W_ + wg;
            float v[8]; float s = 0.f;
            #pragma unroll
            for (int c = 0; c < 8; ++c) { v[c] = src[(size_t)c * HW_]; s += v[c] * v[c]; }
            float inv = 0.35355339059327373f / fmaxf(sqrtf(s), 1e-12f);  // incl 1/sqrt(8)
            #pragma unroll
            for (int c = 0; c < 8; ++c) frl[iw * 68 + gg * 8 + c] = v[c] * inv;
        }
    }

    // own fl vector, normalized (no 1/sqrt(8) here)
    int g = tid & 7, wi = tid >> 3;
    int w = w0 + wi;
    const float* fls = feat_l + (size_t)(b * 64 + g * 8) * HW_ + h * W_ + w;
    float a[8]; float s = 0.f;
    #pragma unroll
    for (int c = 0; c < 8; ++c) { a[c] = fls[(size_t)c * HW_]; s += a[c] * a[c]; }
    float inv = 1.0f / fmaxf(sqrtf(s), 1e-12f);
    #pragma unroll
    for (int c = 0; c < 8; ++c) a[c] *= inv;

    __syncthreads();

    _Float16* dst = baseh + (size_t)((b * DP_ + 4) * HP_ + 4 + h) * WP_ * 8 + (size_t)(4 + w) * 8 + g;
    for (int d = 0; d < D_; ++d) {
        int wd = w - d;
        float acc = 0.f;
        if (wd >= 0) {
            const float* fr = frl + (wd - wbase) * 68 + g * 8;
            acc = a[0]*fr[0] + a[1]*fr[1] + a[2]*fr[2] + a[3]*fr[3]
                + a[4]*fr[4] + a[5]*fr[5] + a[6]*fr[6] + a[7]*fr[7];
        }
        dst[(size_t)d * PLANE_] = (_Float16)acc;
    }
}

// ---------------------------------------------------------------------------
// Kernel 3 (ic-split x4, proven in R10: −5.7 µs): 2D conv(65->32,3x3)
//  +BN+relu+1x1(32->3)+softmax -> 3 planes swp[k].
//  4 groups x ~17 ic each (no read redundancy), LDS reduce, 576 blocks.
// ---------------------------------------------------------------------------
__global__ __launch_bounds__(256) void pred_kernel(const float* __restrict__ feat_l,
                                                   const float* __restrict__ edge,
                                                   const float* __restrict__ wp1T,
                                                   const float* __restrict__ gamma,
                                                   const float* __restrict__ beta,
                                                   const float* __restrict__ mean,
                                                   const float* __restrict__ var,
                                                   const float* __restrict__ w2,
                                                   const float* __restrict__ b2,
                                                   const float* __restrict__ temp,
                                                   float* __restrict__ swp) {
    __shared__ float red[3][64][33];   // pad 33: conflict-free (bank = px+oc)
    int tid = threadIdx.x;
    int px  = tid & 63;
    int grp = tid >> 6;                // 0..3 ic-groups
    int pid = blockIdx.x * 64 + px;    // 0..36863
    int b = pid / HW_; int hw = pid - b * HW_;
    int h = hw / W_;   int w = hw - h * W_;

    int ic0 = grp * 17;
    int ic1 = (grp == 3) ? 65 : ic0 + 17;

    float acc[32];
    #pragma unroll
    for (int i = 0; i < 32; ++i) acc[i] = 0.f;

    for (int ic = ic0; ic < ic1; ++ic) {
        const float* src = (ic < 64) ? (feat_l + (size_t)(b * 64 + ic) * HW_)
                                     : (edge + (size_t)b * HW_);
        float v[9];
        #pragma unroll
        for (int ky = 0; ky < 3; ++ky) {
            int y = h + ky - 1;
            #pragma unroll
            for (int kx = 0; kx < 3; ++kx) {
                int x = w + kx - 1;
                bool ok = (y >= 0) && (y < H_) && (x >= 0) && (x < W_);
                v[ky * 3 + kx] = ok ? src[y * W_ + x] : 0.f;
            }
        }
        #pragma unroll
        for (int t = 0; t < 9; ++t) {
            const float* wrow = wp1T + (ic * 9 + t) * 32;
            float vv = v[t];
            #pragma unroll
            for (int oc = 0; oc < 32; ++oc) acc[oc] = fmaf(vv, wrow[oc], acc[oc]);
        }
    }

    if (grp) {
        #pragma unroll
        for (int oc = 0; oc < 32; ++oc) red[grp - 1][px][oc] = acc[oc];
    }
    __syncthreads();
    if (grp == 0) {
        #pragma unroll
        for (int oc = 0; oc < 32; ++oc)
            acc[oc] += red[0][px][oc] + red[1][px][oc] + red[2][px][oc];

        float l0 = b2[0], l1 = b2[1], l2 = b2[2];
        #pragma unroll
        for (int oc = 0; oc < 32; ++oc) {
            float sc = gamma[oc] / sqrtf(var[oc] + 1e-5f);
            float xb = (acc[oc] - mean[oc]) * sc + beta[oc];
            float r = fmaxf(xb, 0.f);
            l0 = fmaf(w2[0 * 32 + oc], r, l0);
            l1 = fmaf(w2[1 * 32 + oc], r, l1);
            l2 = fmaf(w2[2 * 32 + oc], r, l2);
        }
        float t = fmaxf(temp[0], 0.1f);
        float it = 1.0f / t;
        l0 *= it; l1 *= it; l2 *= it;
        float m = fmaxf(l0, fmaxf(l1, l2));
        float e0 = __expf(l0 - m), e1 = __expf(l1 - m), e2 = __expf(l2 - m);
        float is = 1.0f / (e0 + e1 + e2);
        swp[0 * (B_ * HW_) + pid] = e0 * is;
        swp[1 * (B_ * HW_) + pid] = e1 * is;
        swp[2 * (B_ * HW_) + pid] = e2 * is;
    }
}

// ---------------------------------------------------------------------------
// Kernel 4: MFMA 32x32x16 fused conv — R8 EXACT (best config; ~136 µs).
//  256 thr / (256,2), grid (6,48,B*4) = 2304 blocks (d-sweep 6, refill-depth
//  win), LDS-B 43 KB, chunk-288 XCD swizzle, sw folded into A via pk_mul,
//  2 interleaved acc chains, opaque-index anti-LICM.
//  Closed directions (all measured neutral-to-negative): 8-wave blocks (R4,
//  VGPR collapse), 3-chain epilogue-sw (R6, VGPR collapse), explicit av[42]
//  batch (R7), batch+setprio (R9), launch_bounds(256,4) (R1, spills),
//  halo-zero corr fusion (R11, +19 µs), corr+pred merge (R13, +23 µs).
//  D: col = lane&31 = o, row = (reg&3)+8*(reg>>2)+4*hf = w-offset.
// ---------------------------------------------------------------------------
__global__ __launch_bounds__(256, 2) void fusedconv_mfma32(
        const _Float16* __restrict__ baseh,
        const float* __restrict__ swp,
        const _Float16* __restrict__ bpack,
        const float* __restrict__ bf,
        float* __restrict__ out) {
    __shared__ _Float16 bsh[3 * 14 * 64 * 8];   // 43,008 B

    int tid = threadIdx.x;
    // stage bpack -> LDS (2688 f16x8 chunks)
    {
        const f16x8* srcv = (const f16x8*)bpack;
        f16x8* dstv = (f16x8*)bsh;
        for (int i = tid; i < 2688; i += 256) dstv[i] = srcv[i];
    }

    // XCD-aware bijective swizzle of the linear block id (nwg = 2304 = 8*288)
    int L   = blockIdx.x + 6 * (blockIdx.y + 48 * blockIdx.z);
    int sL  = (L & 7) * 288 + (L >> 3);
    int bx  = sL % 6;
    int byz = sL / 6;
    int by  = byz % 48;
    int bz  = byz / 48;          // 0..7

    int wave = tid >> 6, lane = tid & 63;
    int m = lane & 31, hf = lane >> 5;
    int hh = wave >> 1, dh = wave & 1;
    int w0 = bx * 32;
    int h  = by * 2 + hh;
    int b  = bz >> 2;            // 0..1
    int dq = bz & 3;             // 0..3
    int d0 = dq * 12 + dh * 6;   // 6-d sweep per wave

    // softmax weights as f16 splats (per-lane row m)
    f16x8 swh[3];
    #pragma unroll
    for (int k = 0; k < 3; ++k) {
        float s = swp[k * (B_ * HW_) + b * HW_ + h * W_ + w0 + m];
        _Float16 hs = (_Float16)s;
        f16x8 t;
        #pragma unroll
        for (int j = 0; j < 8; ++j) t[j] = hs;
        swh[k] = t;
    }

    // half-wave address deltas per (scale, class), bytes
    int hdv[3][4];
    #pragma unroll
    for (int k = 0; k < 3; ++k) {
        int dil = 1 << k;
        hdv[k][0] = hf * (2 * dil * HP_ * WP_ * 8 * 2);
        hdv[k][1] = hf * (2 * dil * WP_ * 8 * 2);
        hdv[k][2] = hf * (2 * dil * 8 * 2);
        hdv[k][3] = 0;
    }

    const char* bb = (const char*)baseh;
    char*       ob = (char*)out;

    // byte offset of interior origin (d0-plane, h, w0+m)
    unsigned pm = (unsigned)(((((b * DP_ + 4 + d0) * HP_ + 4 + h) * WP_ + 4 + w0 + m) * 8) * 2);
    float bias = bf[m];   // o = lane&31
    unsigned outoff = (unsigned)((((b * OUT_ + m) * D_ + d0) * HW_ + h * W_ + w0 + 4 * hf) * 4);

    __syncthreads();

    for (int d = 0; d < 6; ++d) {
        // opaque per-iteration LDS byte offset (value lane*16): defeats LICM/hoist
        unsigned bofs = (unsigned)(lane * 16);
        asm volatile("" : "+v"(bofs));
        const char* bshp = (const char*)bsh + bofs;

        f32x16 acc0, acc1;
        #pragma unroll
        for (int i = 0; i < 16; ++i) { acc0[i] = 0.f; acc1[i] = 0.f; }
        #pragma unroll
        for (int k = 0; k < 3; ++k) {
            int dil = 1 << k;
            #pragma unroll
            for (int c = 0; c < 14; ++c) {
                int coff, cls;
                if (c < 9)        { coff = ((-dil * HP_ + (c / 3 - 1) * dil) * WP_ * 8 + (c % 3 - 1) * dil * 8) * 2; cls = 0; }
                else if (c < 12)  { coff = ((-dil) * WP_ * 8 + ((c - 9) - 1) * dil * 8) * 2;                          cls = 1; }
                else if (c == 12) { coff = -dil * 16;                                                                  cls = 2; }
                else              { coff = 0;                                                                          cls = 3; }
                unsigned a = pm + (unsigned)(hdv[k][cls] + coff);
                f16x8 av = *(const f16x8*)(bb + a);
                f16x8 Bv = *(const f16x8*)(bshp + (k * 14 + c) * 1024);
                av = av * swh[k];
                if (c & 1) acc1 = __builtin_amdgcn_mfma_f32_32x32x16_f16(av, Bv, acc1, 0, 0, 0);
                else       acc0 = __builtin_amdgcn_mfma_f32_32x32x16_f16(av, Bv, acc0, 0, 0, 0);
            }
        }
        #pragma unroll
        for (int q = 0; q < 4; ++q) {
            f32x4 v;
            #pragma unroll
            for (int i = 0; i < 4; ++i) v[i] = acc0[4 * q + i] + acc1[4 * q + i] + bias;
            *(f32x4*)(ob + outoff + q * 32) = v;   // rows 8q+4hf..+3, o = m
        }
        pm += PLANE_ * 2;
        outoff += HW_ * 4;
    }
}

// ---------------------------------------------------------------------------
extern "C" void kernel_launch(void* const* d_in, const int* in_sizes, int n_in,
                              void* d_out, int out_size, void* d_ws, size_t ws_size,
                              hipStream_t stream) {
    const float* feat_l   = (const float*)d_in[0];
    const float* feat_r   = (const float*)d_in[1];
    const float* edge     = (const float*)d_in[2];
    const float* w_pred1  = (const float*)d_in[3];
    const float* bn_gamma = (const float*)d_in[4];
    const float* bn_beta  = (const float*)d_in[5];
    const float* bn_mean  = (const float*)d_in[6];
    const float* bn_var   = (const float*)d_in[7];
    const float* w_pred2  = (const float*)d_in[8];
    const float* b_pred2  = (const float*)d_in[9];
    const float* temp     = (const float*)d_in[10];
    const float* w_s      = (const float*)d_in[11];
    const float* w_m      = (const float*)d_in[12];
    const float* w_l      = (const float*)d_in[13];
    const float* w_final  = (const float*)d_in[14];
    const float* b_final  = (const float*)d_in[15];
    float* out = (float*)d_out;

    float* ws = (float*)d_ws;
    _Float16*  baseh = (_Float16*)(ws + OFF_BASEH);
    float*     swp   = ws + OFF_SW;
    _Float16*  bpack = (_Float16*)(ws + OFF_BPACK);
    float*     wp1T  = ws + OFF_WP1T;

    // 0: weight prep
    wtrans_kernel<<<dim3(158), 256, 0, stream>>>(w_s, w_m, w_l, w_final, w_pred1, bpack, wp1T);
    // zero the padded volume (halo must be 0; ws is poisoned each launch).
    // Runtime fill streams at ~6 TB/s — measured better than in-kernel
    // halo zeroing (R11: +19 µs).
    hipMemsetAsync(baseh, 0, (size_t)BASEH_HALFS * sizeof(_Float16), stream);
    // 2: correlation volume -> padded f16 (norm fused in)
    corr_kernel<<<dim3(W_ / 32, H_, B_), 256, 0, stream>>>(feat_l, feat_r, baseh);
    // 3: pred path -> softmax planes (ic-split x4, proven R10)
    pred_kernel<<<dim3(B_ * HW_ / 64), 256, 0, stream>>>(feat_l, edge, wp1T, bn_gamma,
                                                         bn_beta, bn_mean, bn_var,
                                                         w_pred2, b_pred2, temp, swp);
    // 4: MFMA 32x32 fused conv (R8 exact)
    fusedconv_mfma32<<<dim3(W_ / 32, H_ / 2, B_ * 4), 256, 0, stream>>>(baseh, swp, bpack, b_final, out);
}